// Round 3
// baseline (461.790 us; speedup 1.0000x reference)
//
#include <hip/hip_runtime.h>
#include <cstdint>
#include <cstddef>

// GAT layer, N=8192, Fin=128, Fout=64.
// h = elu( softmax_j(mask(leaky_relu(Wh1_i + Wh2_j))) @ Wh )
// Softmax without max-subtraction (e bounded ~|6|): single streaming pass over
// adj (256 MB = the HBM floor), P built in-register in MFMA A-layout.
// R3: SJ=16 (finer tasks, more in-flight adj streams), exp2-domain attention
// logits (Wh1/Wh2 pre-scaled by log2e in phaseA).

#define NN   8192
#define FIN  128
#define FOUT 64
#define SJ   16                // j-split per row-tile: 512*SJ = 8192 wave-tasks
#define JCHUNK (NN / SJ)       // 512 columns per wave

typedef __attribute__((ext_vector_type(8))) short   short8;   // 8 bf16 (4 VGPRs)
typedef __attribute__((ext_vector_type(4))) float   f32x4;

#define LOG2E 1.44269504088896340736f

// ---------------------------------------------------------------- Phase A ---
// One wave per row: Wh[row][f] (f = lane), store bf16 transposed Whbt[f][row],
// wave-reduce Wh1 = Wh.a1, Wh2 = Wh.a2 (both pre-scaled by log2e so phaseB
// can use exp2 directly; leaky_relu commutes with the positive scale).
__global__ __launch_bounds__(256) void gat_phaseA(
    const float* __restrict__ x, const float* __restrict__ W,
    const float* __restrict__ a, unsigned short* __restrict__ Whbt,
    float* __restrict__ Wh1, float* __restrict__ Wh2)
{
  const int wid  = threadIdx.x >> 6;
  const int lane = threadIdx.x & 63;
  const int row  = blockIdx.x * 4 + wid;
  const float* xr = x + row * FIN;          // wave-uniform
  const float a1 = a[lane];
  const float a2 = a[FOUT + lane];
  float acc0 = 0.f, acc1 = 0.f, acc2 = 0.f, acc3 = 0.f;
#pragma unroll 8
  for (int k = 0; k < FIN; k += 4) {
    float4 xv = *(const float4*)(xr + k);
    acc0 = fmaf(xv.x, W[(k + 0) * FOUT + lane], acc0);
    acc1 = fmaf(xv.y, W[(k + 1) * FOUT + lane], acc1);
    acc2 = fmaf(xv.z, W[(k + 2) * FOUT + lane], acc2);
    acc3 = fmaf(xv.w, W[(k + 3) * FOUT + lane], acc3);
  }
  float acc = (acc0 + acc1) + (acc2 + acc3);
  // bf16 round-to-nearest-even
  unsigned int u = __float_as_uint(acc);
  unsigned int r = (u + 0x7FFFu + ((u >> 16) & 1u)) >> 16;
  Whbt[lane * NN + row] = (unsigned short)r;
  float s1 = acc * a1, s2 = acc * a2;
#pragma unroll
  for (int off = 32; off; off >>= 1) {
    s1 += __shfl_xor(s1, off);
    s2 += __shfl_xor(s2, off);
  }
  if (lane == 0) { Wh1[row] = s1 * LOG2E; Wh2[row] = s2 * LOG2E; }
}

// ---------------------------------------------------------------- Phase B ---
// Wave task = (rowTile of 16 rows) x (j-chunk of 512). A-frag (P) computed in
// registers: lane holds rows m=lane&15, k = (lane>>4)*8 + e. Accumulate
// C[16x64] in 4 mfma_16x16x32_bf16 per 32-j block. No LDS, no barriers.
// adj software-prefetched one iteration ahead, nontemporal (protect L2-hot
// Whbt from the 256 MB stream). Logits already in log2 domain -> exp2f.
__global__ __launch_bounds__(256, 4) void gat_phaseB(
    const float* __restrict__ adj, const unsigned short* __restrict__ Whbt,
    const float* __restrict__ Wh1, const float* __restrict__ Wh2,
    float* __restrict__ accbuf, float* __restrict__ denbuf, int nslices)
{
  const int wid  = threadIdx.x >> 6;
  const int lane = threadIdx.x & 63;
  const int task = blockIdx.x * 4 + wid;
  const int rowTile = task / SJ;
  const int jc      = task % SJ;
  const int m = lane & 15;
  const int q = lane >> 4;
  const int row = rowTile * 16 + m;
  const float wh1 = Wh1[row];
  const float* adjrow = adj + (size_t)row * NN;
  const unsigned short* bbase = Whbt + m * NN;   // feature row (ft*16+m)

  f32x4 c0 = {0.f,0.f,0.f,0.f}, c1 = c0, c2 = c0, c3 = c0;
  float rsum = 0.f;

  const int jbeg = jc * JCHUNK;
  const int jend = jbeg + JCHUNK;
  // prime the pipeline
  f32x4 ad0 = __builtin_nontemporal_load((const f32x4*)(adjrow + jbeg + q * 8));
  f32x4 ad1 = __builtin_nontemporal_load((const f32x4*)(adjrow + jbeg + q * 8 + 4));

  for (int jb = jbeg; jb < jend; jb += 32) {
    const int j0 = jb + q * 8;
    // prefetch next iteration's adj (clamped to re-read first block at tail)
    const int jn = (jb + 32 < jend) ? (j0 + 32) : (jbeg + q * 8);
    f32x4 nd0 = __builtin_nontemporal_load((const f32x4*)(adjrow + jn));
    f32x4 nd1 = __builtin_nontemporal_load((const f32x4*)(adjrow + jn + 4));

    f32x4 w20 = *(const f32x4*)(Wh2 + j0);
    f32x4 w21 = *(const f32x4*)(Wh2 + j0 + 4);
    short8 af;
#pragma unroll
    for (int e = 0; e < 4; ++e) {
      {
        float t = wh1 + w20[e];               // log2-domain logit
        t = fmaxf(t, 0.2f * t);               // leaky_relu (scale-invariant)
        float p = exp2f(t) * ad0[e];          // mask: adj is exactly 0.0/1.0
        unsigned int pu = __float_as_uint(p) & 0xFFFF0000u;  // trunc to bf16
        rsum += __uint_as_float(pu);          // denom matches bf16 numerator
        af[e] = (short)(pu >> 16);
      }
      {
        float t = wh1 + w21[e];
        t = fmaxf(t, 0.2f * t);
        float p = exp2f(t) * ad1[e];
        unsigned int pu = __float_as_uint(p) & 0xFFFF0000u;
        rsum += __uint_as_float(pu);
        af[4 + e] = (short)(pu >> 16);
      }
    }
    // B-frags from transposed bf16 Wh (L2-hot, 1 MB): B[n=lane&15][k=q*8+e]
    const unsigned short* bp = bbase + j0;
    c0 = __builtin_amdgcn_mfma_f32_16x16x32_bf16(af, *(const short8*)(bp          ), c0, 0, 0, 0);
    c1 = __builtin_amdgcn_mfma_f32_16x16x32_bf16(af, *(const short8*)(bp + 16 * NN), c1, 0, 0, 0);
    c2 = __builtin_amdgcn_mfma_f32_16x16x32_bf16(af, *(const short8*)(bp + 32 * NN), c2, 0, 0, 0);
    c3 = __builtin_amdgcn_mfma_f32_16x16x32_bf16(af, *(const short8*)(bp + 48 * NN), c3, 0, 0, 0);

    ad0 = nd0; ad1 = nd1;
  }

  // row-sum: combine the 4 k-quads; every lane ends with full sum for row m
  rsum += __shfl_xor(rsum, 16);
  rsum += __shfl_xor(rsum, 32);

  const int slice = (nslices > 1) ? jc : 0;
  float* accout = accbuf + (size_t)slice * (NN * FOUT);
  float* denout = denbuf + slice * NN;
  f32x4 cc[4] = {c0, c1, c2, c3};
  if (nslices > 1) {            // roomy ws: plain per-slice stores
    if (q == 0) denout[row] = rsum;
#pragma unroll
    for (int ft = 0; ft < 4; ++ft)
#pragma unroll
      for (int r = 0; r < 4; ++r)
        accout[(rowTile * 16 + q * 4 + r) * FOUT + ft * 16 + m] = cc[ft][r];
  } else {                      // tight ws: atomic accumulate (zeroed first)
    if (q == 0) atomicAdd(&denout[row], rsum);
#pragma unroll
    for (int ft = 0; ft < 4; ++ft)
#pragma unroll
      for (int r = 0; r < 4; ++r)
        atomicAdd(&accout[(rowTile * 16 + q * 4 + r) * FOUT + ft * 16 + m], cc[ft][r]);
  }
}

// ---------------------------------------------------------------- Phase C ---
// elu(acc/den), vectorized f32x4 per thread.
__global__ __launch_bounds__(256) void gat_phaseC(
    const float* __restrict__ accbuf, const float* __restrict__ denbuf,
    float* __restrict__ out, int nslices)
{
  const int idx4 = blockIdx.x * 256 + threadIdx.x;   // f32x4 index
  const int idx  = idx4 * 4;
  const int row  = idx >> 6;    // FOUT = 64; 4 elems stay within one row
  f32x4 s = {0.f, 0.f, 0.f, 0.f};
  float d = 0.f;
  for (int sl = 0; sl < nslices; ++sl) {
    f32x4 v = *(const f32x4*)(accbuf + (size_t)sl * (NN * FOUT) + idx);
    s += v;
    d += denbuf[sl * NN + row];
  }
  float inv = 1.0f / d;
  f32x4 o;
#pragma unroll
  for (int e = 0; e < 4; ++e) {
    float v = s[e] * inv;
    o[e] = (v > 0.f) ? v : expm1f(v);   // elu, alpha=1
  }
  *(f32x4*)(out + idx) = o;
}

// ------------------------------------------------------------------ launch --
extern "C" void kernel_launch(void* const* d_in, const int* in_sizes, int n_in,
                              void* d_out, int out_size, void* d_ws, size_t ws_size,
                              hipStream_t stream)
{
  const float* x   = (const float*)d_in[0];   // [8192,128]
  const float* adj = (const float*)d_in[1];   // [8192,8192]
  const float* W   = (const float*)d_in[2];   // [128,64]
  const float* a   = (const float*)d_in[3];   // [128,1]
  float* out = (float*)d_out;                 // [8192,64] fp32

  const size_t accEl = (size_t)NN * FOUT;
  const size_t roomyBytes = (size_t)SJ * accEl * 4 + (size_t)SJ * NN * 4
                          + (size_t)NN * 8 + (size_t)FOUT * NN * 2;
  const int nslices = (ws_size >= roomyBytes) ? SJ : 1;

  char* ws = (char*)d_ws;
  float* accbuf = (float*)ws;
  size_t off = (size_t)nslices * accEl * 4;
  float* denbuf = (float*)(ws + off); off += (size_t)nslices * NN * 4;
  float* Wh1 = (float*)(ws + off);    off += (size_t)NN * 4;
  float* Wh2 = (float*)(ws + off);    off += (size_t)NN * 4;
  unsigned short* Whbt = (unsigned short*)(ws + off);

  if (nslices == 1)   // atomic path needs zeroed acc+den (contiguous)
    hipMemsetAsync(accbuf, 0, accEl * 4 + (size_t)NN * 4, stream);

  gat_phaseA<<<NN / 4, 256, 0, stream>>>(x, W, a, Whbt, Wh1, Wh2);
  gat_phaseB<<<(512 * SJ) / 4, 256, 0, stream>>>(adj, Whbt, Wh1, Wh2,
                                                 accbuf, denbuf, nslices);
  gat_phaseC<<<(NN * FOUT) / 4 / 256, 256, 0, stream>>>(accbuf, denbuf, out, nslices);
}

// Round 4
// 436.520 us; speedup vs baseline: 1.0579x; 1.0579x over previous
//
#include <hip/hip_runtime.h>
#include <cstdint>
#include <cstddef>

// GAT layer, N=8192, Fin=128, Fout=64.
// h = elu( softmax_j(mask(leaky_relu(Wh1_i + Wh2_j))) @ Wh )
// Softmax without max-subtraction (e bounded ~|6|): single streaming pass over
// adj (256 MB = the HBM floor), P built in-register in MFMA A-layout.
// R4: SJ=8 (best measured), exp2-domain logits, phaseA amortizes W reads over
// 4 rows/wave (cuts 256 MB of L2 traffic to 64 MB).

#define NN   8192
#define FIN  128
#define FOUT 64
#define SJ   8                 // j-split per row-tile: 512*SJ = 4096 wave-tasks
#define JCHUNK (NN / SJ)       // 1024 columns per wave

typedef __attribute__((ext_vector_type(8))) short   short8;   // 8 bf16 (4 VGPRs)
typedef __attribute__((ext_vector_type(4))) float   f32x4;

#define LOG2E 1.44269504088896340736f

// ---------------------------------------------------------------- Phase A ---
// One wave per 4 rows: Wh[row][f] (f = lane), store bf16 transposed
// Whbt[f][row], wave-reduce Wh1 = Wh.a1, Wh2 = Wh.a2 (pre-scaled by log2e so
// phaseB uses exp2 directly; leaky_relu commutes with positive scaling).
// 4 rows share each W[k][lane] load -> 4x less L2 traffic on W.
__global__ __launch_bounds__(256) void gat_phaseA(
    const float* __restrict__ x, const float* __restrict__ W,
    const float* __restrict__ a, unsigned short* __restrict__ Whbt,
    float* __restrict__ Wh1, float* __restrict__ Wh2)
{
  const int wid  = threadIdx.x >> 6;
  const int lane = threadIdx.x & 63;
  const int row0 = (blockIdx.x * 4 + wid) * 4;
  const float a1 = a[lane];
  const float a2 = a[FOUT + lane];
  float acc[4] = {0.f, 0.f, 0.f, 0.f};
#pragma unroll 4
  for (int k = 0; k < FIN; k += 4) {
    float4 wv0 = make_float4(W[(k+0)*FOUT + lane], W[(k+1)*FOUT + lane],
                             W[(k+2)*FOUT + lane], W[(k+3)*FOUT + lane]);
#pragma unroll
    for (int r = 0; r < 4; ++r) {
      float4 xv = *(const float4*)(x + (row0 + r) * FIN + k);
      acc[r] = fmaf(xv.x, wv0.x, acc[r]);
      acc[r] = fmaf(xv.y, wv0.y, acc[r]);
      acc[r] = fmaf(xv.z, wv0.z, acc[r]);
      acc[r] = fmaf(xv.w, wv0.w, acc[r]);
    }
  }
#pragma unroll
  for (int r = 0; r < 4; ++r) {
    // bf16 round-to-nearest-even
    unsigned int u = __float_as_uint(acc[r]);
    unsigned int rb = (u + 0x7FFFu + ((u >> 16) & 1u)) >> 16;
    Whbt[lane * NN + row0 + r] = (unsigned short)rb;
    float s1 = acc[r] * a1, s2 = acc[r] * a2;
#pragma unroll
    for (int off = 32; off; off >>= 1) {
      s1 += __shfl_xor(s1, off);
      s2 += __shfl_xor(s2, off);
    }
    if (lane == 0) { Wh1[row0 + r] = s1 * LOG2E; Wh2[row0 + r] = s2 * LOG2E; }
  }
}

// ---------------------------------------------------------------- Phase B ---
// Wave task = (rowTile of 16 rows) x (j-chunk of 1024). A-frag (P) computed in
// registers: lane holds rows m=lane&15, k = (lane>>4)*8 + e. Accumulate
// C[16x64] in 4 mfma_16x16x32_bf16 per 32-j block. No LDS, no barriers.
// adj software-prefetched one iteration ahead, nontemporal (protect L2-hot
// Whbt from the 256 MB stream). Logits in log2 domain -> exp2f.
__global__ __launch_bounds__(256, 4) void gat_phaseB(
    const float* __restrict__ adj, const unsigned short* __restrict__ Whbt,
    const float* __restrict__ Wh1, const float* __restrict__ Wh2,
    float* __restrict__ accbuf, float* __restrict__ denbuf, int nslices)
{
  const int wid  = threadIdx.x >> 6;
  const int lane = threadIdx.x & 63;
  const int task = blockIdx.x * 4 + wid;
  const int rowTile = task / SJ;
  const int jc      = task % SJ;
  const int m = lane & 15;
  const int q = lane >> 4;
  const int row = rowTile * 16 + m;
  const float wh1 = Wh1[row];
  const float* adjrow = adj + (size_t)row * NN;
  const unsigned short* bbase = Whbt + m * NN;   // feature row (ft*16+m)

  f32x4 c0 = {0.f,0.f,0.f,0.f}, c1 = c0, c2 = c0, c3 = c0;
  float rsum = 0.f;

  const int jbeg = jc * JCHUNK;
  const int jend = jbeg + JCHUNK;
  // prime the pipeline
  f32x4 ad0 = __builtin_nontemporal_load((const f32x4*)(adjrow + jbeg + q * 8));
  f32x4 ad1 = __builtin_nontemporal_load((const f32x4*)(adjrow + jbeg + q * 8 + 4));

  for (int jb = jbeg; jb < jend; jb += 32) {
    const int j0 = jb + q * 8;
    // prefetch next iteration's adj (clamped to re-read first block at tail)
    const int jn = (jb + 32 < jend) ? (j0 + 32) : (jbeg + q * 8);
    f32x4 nd0 = __builtin_nontemporal_load((const f32x4*)(adjrow + jn));
    f32x4 nd1 = __builtin_nontemporal_load((const f32x4*)(adjrow + jn + 4));

    f32x4 w20 = *(const f32x4*)(Wh2 + j0);
    f32x4 w21 = *(const f32x4*)(Wh2 + j0 + 4);
    short8 af;
#pragma unroll
    for (int e = 0; e < 4; ++e) {
      {
        float t = wh1 + w20[e];               // log2-domain logit
        t = fmaxf(t, 0.2f * t);               // leaky_relu (scale-invariant)
        float p = exp2f(t) * ad0[e];          // mask: adj is exactly 0.0/1.0
        unsigned int pu = __float_as_uint(p) & 0xFFFF0000u;  // trunc to bf16
        rsum += __uint_as_float(pu);          // denom matches bf16 numerator
        af[e] = (short)(pu >> 16);
      }
      {
        float t = wh1 + w21[e];
        t = fmaxf(t, 0.2f * t);
        float p = exp2f(t) * ad1[e];
        unsigned int pu = __float_as_uint(p) & 0xFFFF0000u;
        rsum += __uint_as_float(pu);
        af[4 + e] = (short)(pu >> 16);
      }
    }
    // B-frags from transposed bf16 Wh (L2-hot, 1 MB): B[n=lane&15][k=q*8+e]
    const unsigned short* bp = bbase + j0;
    c0 = __builtin_amdgcn_mfma_f32_16x16x32_bf16(af, *(const short8*)(bp          ), c0, 0, 0, 0);
    c1 = __builtin_amdgcn_mfma_f32_16x16x32_bf16(af, *(const short8*)(bp + 16 * NN), c1, 0, 0, 0);
    c2 = __builtin_amdgcn_mfma_f32_16x16x32_bf16(af, *(const short8*)(bp + 32 * NN), c2, 0, 0, 0);
    c3 = __builtin_amdgcn_mfma_f32_16x16x32_bf16(af, *(const short8*)(bp + 48 * NN), c3, 0, 0, 0);

    ad0 = nd0; ad1 = nd1;
  }

  // row-sum: combine the 4 k-quads; every lane ends with full sum for row m
  rsum += __shfl_xor(rsum, 16);
  rsum += __shfl_xor(rsum, 32);

  const int slice = (nslices > 1) ? jc : 0;
  float* accout = accbuf + (size_t)slice * (NN * FOUT);
  float* denout = denbuf + slice * NN;
  f32x4 cc[4] = {c0, c1, c2, c3};
  if (nslices > 1) {            // roomy ws: plain per-slice stores
    if (q == 0) denout[row] = rsum;
#pragma unroll
    for (int ft = 0; ft < 4; ++ft)
#pragma unroll
      for (int r = 0; r < 4; ++r)
        accout[(rowTile * 16 + q * 4 + r) * FOUT + ft * 16 + m] = cc[ft][r];
  } else {                      // tight ws: atomic accumulate (zeroed first)
    if (q == 0) atomicAdd(&denout[row], rsum);
#pragma unroll
    for (int ft = 0; ft < 4; ++ft)
#pragma unroll
      for (int r = 0; r < 4; ++r)
        atomicAdd(&accout[(rowTile * 16 + q * 4 + r) * FOUT + ft * 16 + m], cc[ft][r]);
  }
}

// ---------------------------------------------------------------- Phase C ---
// elu(acc/den), vectorized f32x4 per thread.
__global__ __launch_bounds__(256) void gat_phaseC(
    const float* __restrict__ accbuf, const float* __restrict__ denbuf,
    float* __restrict__ out, int nslices)
{
  const int idx4 = blockIdx.x * 256 + threadIdx.x;   // f32x4 index
  const int idx  = idx4 * 4;
  const int row  = idx >> 6;    // FOUT = 64; 4 elems stay within one row
  f32x4 s = {0.f, 0.f, 0.f, 0.f};
  float d = 0.f;
  for (int sl = 0; sl < nslices; ++sl) {
    f32x4 v = *(const f32x4*)(accbuf + (size_t)sl * (NN * FOUT) + idx);
    s += v;
    d += denbuf[sl * NN + row];
  }
  float inv = 1.0f / d;
  f32x4 o;
#pragma unroll
  for (int e = 0; e < 4; ++e) {
    float v = s[e] * inv;
    o[e] = (v > 0.f) ? v : expm1f(v);   // elu, alpha=1
  }
  *(f32x4*)(out + idx) = o;
}

// ------------------------------------------------------------------ launch --
extern "C" void kernel_launch(void* const* d_in, const int* in_sizes, int n_in,
                              void* d_out, int out_size, void* d_ws, size_t ws_size,
                              hipStream_t stream)
{
  const float* x   = (const float*)d_in[0];   // [8192,128]
  const float* adj = (const float*)d_in[1];   // [8192,8192]
  const float* W   = (const float*)d_in[2];   // [128,64]
  const float* a   = (const float*)d_in[3];   // [128,1]
  float* out = (float*)d_out;                 // [8192,64] fp32

  const size_t accEl = (size_t)NN * FOUT;
  const size_t roomyBytes = (size_t)SJ * accEl * 4 + (size_t)SJ * NN * 4
                          + (size_t)NN * 8 + (size_t)FOUT * NN * 2;
  const int nslices = (ws_size >= roomyBytes) ? SJ : 1;

  char* ws = (char*)d_ws;
  float* accbuf = (float*)ws;
  size_t off = (size_t)nslices * accEl * 4;
  float* denbuf = (float*)(ws + off); off += (size_t)nslices * NN * 4;
  float* Wh1 = (float*)(ws + off);    off += (size_t)NN * 4;
  float* Wh2 = (float*)(ws + off);    off += (size_t)NN * 4;
  unsigned short* Whbt = (unsigned short*)(ws + off);

  if (nslices == 1)   // atomic path needs zeroed acc+den (contiguous)
    hipMemsetAsync(accbuf, 0, accEl * 4 + (size_t)NN * 4, stream);

  gat_phaseA<<<NN / 16, 256, 0, stream>>>(x, W, a, Whbt, Wh1, Wh2);
  gat_phaseB<<<(512 * SJ) / 4, 256, 0, stream>>>(adj, Whbt, Wh1, Wh2,
                                                 accbuf, denbuf, nslices);
  gat_phaseC<<<(NN * FOUT) / 4 / 256, 256, 0, stream>>>(accbuf, denbuf, out, nslices);
}